// Round 13
// baseline (129.144 us; speedup 1.0000x reference)
//
#include <hip/hip_runtime.h>
#include <stdint.h>

#define OUTD 4000
#define NPAD 4096
#define CC 16
#define WW 48
#define HH 48
#define BB 128
#define KD 768          // C*H contraction depth
#define MD 6144         // B*W rows
#define EPSF 1e-6f
#define XPB 2304        // blocks for x-conversion in prep_all

using short8 = __attribute__((ext_vector_type(8))) short;
using f32x4  = __attribute__((ext_vector_type(4))) float;

static __device__ __forceinline__ unsigned short f2bf(float f) {
  union { float f; unsigned int u; } v; v.f = f;
  unsigned int u = v.u;
  unsigned int r = (u + 0x7FFFu + ((u >> 16) & 1u)) >> 16;
  return (unsigned short)r;
}

// ---------------- Fused prep: blocks [0,XPB) convert x -> A (bf16, merged (c,h) K axis);
// blocks [XPB, XPB+1024) normalize weights -> Qt (bf16) + wnT (f32, [48][4096]).
__global__ __launch_bounds__(256)
void prep_all(const float* __restrict__ x,
              const float* __restrict__ width,
              const float* __restrict__ height,
              const float* __restrict__ feat,
              unsigned short* __restrict__ A,
              unsigned short* __restrict__ Qt,
              float* __restrict__ wnT) {
  __shared__ float smw[4][WW];
  int bid = blockIdx.x;
  if (bid < XPB) {
    int t = bid * 256 + threadIdx.x;      // XPB*256 == BB*CC*WW*HH/8 exactly
    int e = t * 8;
    int h0 = e % HH;                      // 8 | 48: the 8 elems share (b,c,w)
    int w = (e / HH) % WW;
    int c = (e / (HH * WW)) % CC;
    int b = e / (HH * WW * CC);
    float4 v0 = *(const float4*)(x + e);
    float4 v1 = *(const float4*)(x + e + 4);
    short8 o;
    o[0] = (short)f2bf(v0.x); o[1] = (short)f2bf(v0.y);
    o[2] = (short)f2bf(v0.z); o[3] = (short)f2bf(v0.w);
    o[4] = (short)f2bf(v1.x); o[5] = (short)f2bf(v1.y);
    o[6] = (short)f2bf(v1.z); o[7] = (short)f2bf(v1.w);
    *(short8*)&A[(size_t)(b * WW + w) * KD + c * HH + h0] = o;
  } else {
    int lane = threadIdx.x & 63;
    int wv = threadIdx.x >> 6;            // wave 0..3
    int nbase = (bid - XPB) * 4;
    int n = nbase + wv;                   // 0..4095
    bool valid = (n < OUTD);
    float hv = (valid && lane < HH) ? height[n * HH + lane] : 0.f;
    float wvv = (valid && lane < WW) ? width[n * WW + lane] : 0.f;
    float hs = hv * hv, wsum = wvv * wvv;
    #pragma unroll
    for (int off = 32; off > 0; off >>= 1) {
      hs += __shfl_xor(hs, off);
      wsum += __shfl_xor(wsum, off);
    }
    float hnorm = rsqrtf(hs + EPSF);
    float wnorm = rsqrtf(wsum + EPSF);
    if (lane < WW) smw[wv][lane] = wvv * wnorm;   // 0 for invalid n
    if (valid) {
      #pragma unroll
      for (int i = lane; i < KD; i += 64) {
        int c = i / HH, h = i % HH;
        Qt[(size_t)n * KD + i] = f2bf(feat[n * CC + c] * height[n * HH + h] * hnorm);
      }
    } else {
      #pragma unroll
      for (int i = lane; i < KD; i += 64) Qt[(size_t)n * KD + i] = 0;
    }
    __syncthreads();
    if (threadIdx.x < WW) {
      int w = threadIdx.x;
      float4 o = make_float4(smw[0][w], smw[1][w], smw[2][w], smw[3][w]);
      *(float4*)&wnT[w * NPAD + nbase] = o;
    }
  }
}

// ---------------- Main GEMM, LDS-FREE: P = A (6144x768) * Qt^T (768x4096) + fused epilogue.
// Operands are L2/L3-resident; MFMA fragments ARE coalesced global patterns, so each wave
// loads its A/B fragments global->VGPR directly. No LDS, no barriers, no staging: waves
// fully independent (TLP from 2 blocks/CU + 2 waves/SIMD). Block = 4 waves sharing one
// 96-row m-slice (A re-read x4 -> L1 hits); wave tile 96x64, acc 96 regs.
// Per k-step (K=32): 10 global_load_dwordx4 (imm offsets, zero VALU) + 24 MFMA,
// register double-buffered one step ahead.
__global__ __launch_bounds__(256, 2)
void gemm_main(const unsigned short* __restrict__ A,   // [6144][768] bf16 bits
               const unsigned short* __restrict__ Qt,  // [4096][768] bf16 bits
               const float* __restrict__ wnT,          // [48][4096]
               const float* __restrict__ bias,         // [4000]
               float* __restrict__ out) {              // [128][4000]
  int tid = threadIdx.x;
  int lane = tid & 63;
  int wid = tid >> 6;          // 0..3 -> 64-col subtile

  // 1024 blocks: XCD k (= bid&7) owns m-slices [8k, 8k+8) (A-share 1.15MB, L2-resident),
  // sweeps 16 n-panels (B panel 393KB, L2-resident while hot).
  int bid = blockIdx.x;        // 0..1023
  int xcd = bid & 7;
  int i = bid >> 3;            // 0..127
  int my = xcd * 8 + (i & 7);  // m-slice 0..63 (96 rows each)
  int nb = i >> 3;             // n-panel 0..15 (256 cols each)
  int m0 = my * 96;
  int n0 = nb * 256 + wid * 64;

  int q16 = lane & 15;
  int hi = lane >> 4;          // 0..3

  // Fragment base pointers (fixed; k advances via 16B-aligned immediate offsets).
  const unsigned short* pa[6];
  const unsigned short* pb[4];
  #pragma unroll
  for (int mi = 0; mi < 6; ++mi)
    pa[mi] = A + (size_t)(m0 + mi * 16 + q16) * KD + hi * 8;
  #pragma unroll
  for (int ni = 0; ni < 4; ++ni)
    pb[ni] = Qt + (size_t)(n0 + ni * 16 + q16) * KD + hi * 8;

  f32x4 acc[6][4] = {};
  short8 raA[6], rbA[4], raB[6], rbB[4];

#define LOADSET(ra, rb, s)                                             \
  { _Pragma("unroll")                                                  \
    for (int mi = 0; mi < 6; ++mi)                                     \
      ra[mi] = *(const short8*)(pa[mi] + (s) * 32);                    \
    _Pragma("unroll")                                                  \
    for (int ni = 0; ni < 4; ++ni)                                     \
      rb[ni] = *(const short8*)(pb[ni] + (s) * 32); }

#define MFMA24(ra, rb)                                                 \
  { _Pragma("unroll")                                                  \
    for (int ni = 0; ni < 4; ++ni)                                     \
      _Pragma("unroll")                                                \
      for (int mi = 0; mi < 6; ++mi)                                   \
        acc[mi][ni] = __builtin_amdgcn_mfma_f32_16x16x32_bf16(ra[mi], rb[ni], acc[mi][ni], 0, 0, 0); }

  LOADSET(raA, rbA, 0);
  #pragma unroll
  for (int s = 0; s < 24; ++s) {        // 24 k-steps of K=32
    if (s & 1) {
      if (s + 1 < 24) LOADSET(raA, rbA, s + 1);
      MFMA24(raB, rbB);
    } else {
      if (s + 1 < 24) LOADSET(raB, rbB, s + 1);
      MFMA24(raA, rbA);
    }
  }

  // ---- Epilogue: y[b,n] = sum_w wnT[w][n] * P[(b,w),n] + bias[n]
  // wave rows: mi*16 + hi*4 + rr; batch = my*2 + (mi>=3); w = (mi%3)*16 + hi*4 + rr.
  int b0 = my * 2;
  #pragma unroll
  for (int ni = 0; ni < 4; ++ni) {
    int ng = n0 + ni * 16 + q16;
    float s0 = 0.f, s1 = 0.f;
    #pragma unroll
    for (int mi = 0; mi < 3; ++mi) {
      int wbase = mi * 16 + hi * 4;
      f32x4 va = acc[mi][ni];
      f32x4 vb = acc[mi + 3][ni];
      #pragma unroll
      for (int r = 0; r < 4; ++r) {
        float t = wnT[(wbase + r) * NPAD + ng];
        s0 += t * va[r];
        s1 += t * vb[r];
      }
    }
    s0 += __shfl_xor(s0, 16); s0 += __shfl_xor(s0, 32);
    s1 += __shfl_xor(s1, 16); s1 += __shfl_xor(s1, 32);
    if (hi == 0 && ng < OUTD) {
      float bv = bias[ng];
      out[(size_t)b0 * OUTD + ng] = s0 + bv;
      out[(size_t)(b0 + 1) * OUTD + ng] = s1 + bv;
    }
  }
#undef LOADSET
#undef MFMA24
}

extern "C" void kernel_launch(void* const* d_in, const int* in_sizes, int n_in,
                              void* d_out, int out_size, void* d_ws, size_t ws_size,
                              hipStream_t stream) {
  const float* x      = (const float*)d_in[0];
  const float* width  = (const float*)d_in[1];
  const float* height = (const float*)d_in[2];
  const float* feat   = (const float*)d_in[3];
  const float* bias   = (const float*)d_in[4];
  float* out = (float*)d_out;

  char* ws = (char*)d_ws;
  unsigned short* A  = (unsigned short*)ws;                        // 6144*768*2 = 9,437,184
  unsigned short* Qt = (unsigned short*)(ws + 9437184);            // 4096*768*2 = 6,291,456
  float* wnT         = (float*)(ws + 9437184 + 6291456);           // 48*4096*4  =   786,432

  prep_all<<<dim3(XPB + NPAD / 4), dim3(256), 0, stream>>>(x, width, height, feat, A, Qt, wnT);
  gemm_main<<<dim3(1024), dim3(256), 0, stream>>>(A, Qt, wnT, bias, out);
}

// Round 14
// 67.978 us; speedup vs baseline: 1.8998x; 1.8998x over previous
//
#include <hip/hip_runtime.h>
#include <stdint.h>

#define OUTD 4000
#define NPAD 4096
#define CC 16
#define WW 48
#define HH 48
#define BB 128
#define KD 768          // C*H contraction depth
#define MD 6144         // B*W rows
#define EPSF 1e-6f

#define BM 96           // 2 batches * 48 w
#define BN 128
#define BKU 32          // K elems per unit
#define UNITS 24        // 768/32
#define AELEMS (BM * BKU)              // 3072 elems (= 6 chunks of 512)
#define SLOT_ELEMS ((BM + BN) * BKU)   // 7168 elems = 14336 B
#define THREADS 256
#define XPB 2304        // blocks for x-conversion in prep_all

using short8 = __attribute__((ext_vector_type(8))) short;
using f32x4  = __attribute__((ext_vector_type(4))) float;

static __device__ __forceinline__ unsigned short f2bf(float f) {
  union { float f; unsigned int u; } v; v.f = f;
  unsigned int u = v.u;
  unsigned int r = (u + 0x7FFFu + ((u >> 16) & 1u)) >> 16;
  return (unsigned short)r;
}

// ---------------- Fused prep: blocks [0,XPB) convert x -> A (bf16, merged (c,h) K axis);
// blocks [XPB, XPB+1024) normalize weights -> Qt (bf16) + wnT (f32, [48][4096]).
__global__ __launch_bounds__(256)
void prep_all(const float* __restrict__ x,
              const float* __restrict__ width,
              const float* __restrict__ height,
              const float* __restrict__ feat,
              unsigned short* __restrict__ A,
              unsigned short* __restrict__ Qt,
              float* __restrict__ wnT) {
  __shared__ float smw[4][WW];
  int bid = blockIdx.x;
  if (bid < XPB) {
    int t = bid * 256 + threadIdx.x;      // XPB*256 == BB*CC*WW*HH/8 exactly
    int e = t * 8;
    int h0 = e % HH;                      // 8 | 48: the 8 elems share (b,c,w)
    int w = (e / HH) % WW;
    int c = (e / (HH * WW)) % CC;
    int b = e / (HH * WW * CC);
    float4 v0 = *(const float4*)(x + e);
    float4 v1 = *(const float4*)(x + e + 4);
    short8 o;
    o[0] = (short)f2bf(v0.x); o[1] = (short)f2bf(v0.y);
    o[2] = (short)f2bf(v0.z); o[3] = (short)f2bf(v0.w);
    o[4] = (short)f2bf(v1.x); o[5] = (short)f2bf(v1.y);
    o[6] = (short)f2bf(v1.z); o[7] = (short)f2bf(v1.w);
    *(short8*)&A[(size_t)(b * WW + w) * KD + c * HH + h0] = o;
  } else {
    int lane = threadIdx.x & 63;
    int wv = threadIdx.x >> 6;            // wave 0..3
    int nbase = (bid - XPB) * 4;
    int n = nbase + wv;                   // 0..4095
    bool valid = (n < OUTD);
    float hv = (valid && lane < HH) ? height[n * HH + lane] : 0.f;
    float wvv = (valid && lane < WW) ? width[n * WW + lane] : 0.f;
    float hs = hv * hv, wsum = wvv * wvv;
    #pragma unroll
    for (int off = 32; off > 0; off >>= 1) {
      hs += __shfl_xor(hs, off);
      wsum += __shfl_xor(wsum, off);
    }
    float hnorm = rsqrtf(hs + EPSF);
    float wnorm = rsqrtf(wsum + EPSF);
    if (lane < WW) smw[wv][lane] = wvv * wnorm;   // 0 for invalid n
    if (valid) {
      #pragma unroll
      for (int i = lane; i < KD; i += 64) {
        int c = i / HH, h = i % HH;
        Qt[(size_t)n * KD + i] = f2bf(feat[n * CC + c] * height[n * HH + h] * hnorm);
      }
    } else {
      #pragma unroll
      for (int i = lane; i < KD; i += 64) Qt[(size_t)n * KD + i] = 0;
    }
    __syncthreads();
    if (threadIdx.x < WW) {
      int w = threadIdx.x;
      float4 o = make_float4(smw[0][w], smw[1][w], smw[2][w], smw[3][w]);
      *(float4*)&wnT[w * NPAD + nbase] = o;
    }
  }
}

// ---------------- Main GEMM: P = A (6144x768) * Qt^T (768x4096), fused w-reduction epilogue.
// m97-residency shape: 96x128 tile, 4 waves (2m x 2n), wave tile 48x64 (acc 48 regs,
// ~105 total/wave). Ring of 3 x 14KB LDS slots = 43KB -> 3 blocks/CU co-resident with
// independent barrier domains (the cross-block overlap every 1-block design lacked).
// One barrier/unit, counted vmcnt(3) (2-unit stage lead), compiler-scheduled lgkm.
__global__ __launch_bounds__(THREADS, 3)
void gemm_main(const unsigned short* __restrict__ A,   // [6144][768] bf16 bits
               const unsigned short* __restrict__ Qt,  // [4096][768] bf16 bits
               const float* __restrict__ wnT,          // [48][4096]
               const float* __restrict__ bias,         // [4000]
               float* __restrict__ out) {              // [128][4000]
  __shared__ unsigned short S[3 * SLOT_ELEMS];   // 43008 B -> 3 blocks/CU

  int tid = threadIdx.x;
  int lane = tid & 63;
  int wid = tid >> 6;          // 0..3
  int wm = wid >> 1;           // 0..1 -> 48-row slice (one batch)
  int wn = wid & 1;            // 0..1 -> 64-col half

  // 2048 blocks: XCD k (= bid&7) owns by in [8k, 8k+8) (A-share 1.15MB, L2-resident),
  // sweeps 32 n-tiles.
  int bid = blockIdx.x;        // 0..2047
  int xcd = bid & 7;
  int i = bid >> 3;            // 0..255
  int by = xcd * 8 + (i & 7);  // 0..63
  int bx = i >> 3;             // 0..31
  int n0 = bx * BN;
  int m0 = by * BM;

  // ---- staging: 14 chunks per unit (chunk: 16 rows x 32 elems = 1KB).
  // Chunks 0..5 = A rows [c*16, c*16+16); chunks 6..13 = B rows [(c-6)*16, ...).
  // LDS chunk base = c*512 (A region 0..3071, B region 3072..7167, contiguous).
  // Wave assignment: w0{0,1,6,7} w1{2,3,8,9} w2{4,5,10} w3{11,12,13} -> L = 4,4,3,3.
  // Global source granule XOR-pre-swizzled (granule 16B, row 64B):
  // LDS[row][g*8..] holds global[row][(g ^ ((row>>1)&3))*8..].
  int lrow = lane >> 2;              // 0..15 row within chunk
  int g = lane & 3;                  // granule
  int gsw = (g ^ ((lrow >> 1) & 3)) * 8;
  int myc[4];
  int nl;
  if (wid == 0)      { myc[0] = 0;  myc[1] = 1;  myc[2] = 6;  myc[3] = 7;  nl = 4; }
  else if (wid == 1) { myc[0] = 2;  myc[1] = 3;  myc[2] = 8;  myc[3] = 9;  nl = 4; }
  else if (wid == 2) { myc[0] = 4;  myc[1] = 5;  myc[2] = 10; myc[3] = 10; nl = 3; }
  else               { myc[0] = 11; myc[1] = 12; myc[2] = 13; myc[3] = 13; nl = 3; }
  const unsigned short* gp[4];
  int dofs[4];
  #pragma unroll
  for (int j = 0; j < 4; ++j) {
    int c = myc[j];
    gp[j] = (c < 6 ? A + (size_t)(m0 + c * 16 + lrow) * KD
                   : Qt + (size_t)(n0 + (c - 6) * 16 + lrow) * KD) + gsw;
    dofs[j] = c * 512;
  }

#define SLOTB(u) (((u) % 3) * SLOT_ELEMS)
#define STAGE(u)                                                                  \
  { _Pragma("unroll")                                                             \
    for (int j = 0; j < 4; ++j)                                                   \
      if (j < nl)                                                                 \
        __builtin_amdgcn_global_load_lds(                                         \
            (const __attribute__((address_space(1))) void*)(gp[j] + (u) * BKU),   \
            (__attribute__((address_space(3))) void*)(&S[SLOTB(u) + dofs[j]]), 16, 0, 0); }

  // ---- ds_read offsets (elem); rows 32 elems (64B); swizzle matches staging.
  int q16 = lane & 15;
  int hi = lane >> 4;                // 0..3 -> k-granule
  int kgr = ((hi ^ ((q16 >> 1) & 3))) * 8;
  int arow = (wm * 48 + q16) * BKU + kgr;            // + mi*16*32
  int brow = AELEMS + (wn * 64 + q16) * BKU + kgr;   // + ni*16*32

  f32x4 acc[3][4] = {};

  // Prologue: 2 units in flight.
  STAGE(0); STAGE(1);

  #pragma unroll
  for (int u = 0; u < UNITS; ++u) {
    if (u < UNITS - 1) asm volatile("s_waitcnt vmcnt(3)" ::: "memory");
    else               asm volatile("s_waitcnt vmcnt(0)" ::: "memory");
    __builtin_amdgcn_s_barrier();              // slot u staged by all waves;
                                               // slot (u+2)%3's last readers (unit u-1) done
    if (u + 2 < UNITS) STAGE(u + 2);

    const unsigned short* sb = &S[SLOTB(u)];
    short8 af[3], bf[4];
    #pragma unroll
    for (int mi = 0; mi < 3; ++mi)
      af[mi] = *(const short8*)&sb[arow + mi * 16 * BKU];
    #pragma unroll
    for (int ni = 0; ni < 4; ++ni)
      bf[ni] = *(const short8*)&sb[brow + ni * 16 * BKU];
    __builtin_amdgcn_s_setprio(1);
    #pragma unroll
    for (int ni = 0; ni < 4; ++ni)
      #pragma unroll
      for (int mi = 0; mi < 3; ++mi)
        acc[mi][ni] = __builtin_amdgcn_mfma_f32_16x16x32_bf16(af[mi], bf[ni], acc[mi][ni], 0, 0, 0);
    __builtin_amdgcn_s_setprio(0);
    // all 7 ds_reads are consumed by the MFMAs above -> retired before next barrier
  }

  // ---- Epilogue: y[b,n] = sum_w wnT[w][n] * P[(b,w),n] + bias[n]
  // wave rows: wm*48 + mi*16 + hi*4 + r -> batch b = by*2 + wm, w = mi*16 + hi*4 + r.
  int b = by * 2 + wm;
  #pragma unroll
  for (int ni = 0; ni < 4; ++ni) {
    int ng = n0 + wn * 64 + ni * 16 + q16;
    float s = 0.f;
    #pragma unroll
    for (int mi = 0; mi < 3; ++mi) {
      int wbase = mi * 16 + hi * 4;
      f32x4 v = acc[mi][ni];
      #pragma unroll
      for (int r = 0; r < 4; ++r)
        s += wnT[(wbase + r) * NPAD + ng] * v[r];
    }
    s += __shfl_xor(s, 16);
    s += __shfl_xor(s, 32);
    if (hi == 0 && ng < OUTD)
      out[(size_t)b * OUTD + ng] = s + bias[ng];
  }
#undef STAGE
#undef SLOTB
}

extern "C" void kernel_launch(void* const* d_in, const int* in_sizes, int n_in,
                              void* d_out, int out_size, void* d_ws, size_t ws_size,
                              hipStream_t stream) {
  const float* x      = (const float*)d_in[0];
  const float* width  = (const float*)d_in[1];
  const float* height = (const float*)d_in[2];
  const float* feat   = (const float*)d_in[3];
  const float* bias   = (const float*)d_in[4];
  float* out = (float*)d_out;

  char* ws = (char*)d_ws;
  unsigned short* A  = (unsigned short*)ws;                        // 6144*768*2 = 9,437,184
  unsigned short* Qt = (unsigned short*)(ws + 9437184);            // 4096*768*2 = 6,291,456
  float* wnT         = (float*)(ws + 9437184 + 6291456);           // 48*4096*4  =   786,432

  prep_all<<<dim3(XPB + NPAD / 4), dim3(256), 0, stream>>>(x, width, height, feat, A, Qt, wnT);
  gemm_main<<<dim3(2048), dim3(THREADS), 0, stream>>>(A, Qt, wnT, bias, out);
}

// Round 15
// 54.676 us; speedup vs baseline: 2.3620x; 1.2433x over previous
//
#include <hip/hip_runtime.h>
#include <stdint.h>

#define OUTD 4000
#define NPAD 4096
#define CC 16
#define WW 48
#define HH 48
#define BB 128
#define KD 768          // C*H contraction depth
#define MD 6144         // B*W rows
#define EPSF 1e-6f

#define BM 192          // 4 batches * 48 w
#define BNB 256
#define BKU 32          // K elems per unit
#define UNITS 24        // 768/32
#define AELEMS (BM * BKU)              // 6144 elems = 12 chunks
#define SLOT_ELEMS ((BM + BNB) * BKU)  // 14336 elems = 28 KB
#define THREADS 256
#define XPB 2304        // blocks for x-conversion in prep_all

using short8 = __attribute__((ext_vector_type(8))) short;
using f32x4  = __attribute__((ext_vector_type(4))) float;

static __device__ __forceinline__ unsigned short f2bf(float f) {
  union { float f; unsigned int u; } v; v.f = f;
  unsigned int u = v.u;
  unsigned int r = (u + 0x7FFFu + ((u >> 16) & 1u)) >> 16;
  return (unsigned short)r;
}

// ---------------- Fused prep: blocks [0,XPB) convert x -> A (bf16, merged (c,h) K axis);
// blocks [XPB, XPB+1024) normalize weights -> Qt (bf16) + wnT (f32, [48][4096]).
__global__ __launch_bounds__(256)
void prep_all(const float* __restrict__ x,
              const float* __restrict__ width,
              const float* __restrict__ height,
              const float* __restrict__ feat,
              unsigned short* __restrict__ A,
              unsigned short* __restrict__ Qt,
              float* __restrict__ wnT) {
  __shared__ float smw[4][WW];
  int bid = blockIdx.x;
  if (bid < XPB) {
    int t = bid * 256 + threadIdx.x;      // XPB*256 == BB*CC*WW*HH/8 exactly
    int e = t * 8;
    int h0 = e % HH;                      // 8 | 48: the 8 elems share (b,c,w)
    int w = (e / HH) % WW;
    int c = (e / (HH * WW)) % CC;
    int b = e / (HH * WW * CC);
    float4 v0 = *(const float4*)(x + e);
    float4 v1 = *(const float4*)(x + e + 4);
    short8 o;
    o[0] = (short)f2bf(v0.x); o[1] = (short)f2bf(v0.y);
    o[2] = (short)f2bf(v0.z); o[3] = (short)f2bf(v0.w);
    o[4] = (short)f2bf(v1.x); o[5] = (short)f2bf(v1.y);
    o[6] = (short)f2bf(v1.z); o[7] = (short)f2bf(v1.w);
    *(short8*)&A[(size_t)(b * WW + w) * KD + c * HH + h0] = o;
  } else {
    int lane = threadIdx.x & 63;
    int wv = threadIdx.x >> 6;            // wave 0..3
    int nbase = (bid - XPB) * 4;
    int n = nbase + wv;                   // 0..4095
    bool valid = (n < OUTD);
    float hv = (valid && lane < HH) ? height[n * HH + lane] : 0.f;
    float wvv = (valid && lane < WW) ? width[n * WW + lane] : 0.f;
    float hs = hv * hv, wsum = wvv * wvv;
    #pragma unroll
    for (int off = 32; off > 0; off >>= 1) {
      hs += __shfl_xor(hs, off);
      wsum += __shfl_xor(wsum, off);
    }
    float hnorm = rsqrtf(hs + EPSF);
    float wnorm = rsqrtf(wsum + EPSF);
    if (lane < WW) smw[wv][lane] = wvv * wnorm;   // 0 for invalid n
    if (valid) {
      #pragma unroll
      for (int i = lane; i < KD; i += 64) {
        int c = i / HH, h = i % HH;
        Qt[(size_t)n * KD + i] = f2bf(feat[n * CC + c] * height[n * HH + h] * hnorm);
      }
    } else {
      #pragma unroll
      for (int i = lane; i < KD; i += 64) Qt[(size_t)n * KD + i] = 0;
    }
    __syncthreads();
    if (threadIdx.x < WW) {
      int w = threadIdx.x;
      float4 o = make_float4(smw[0][w], smw[1][w], smw[2][w], smw[3][w]);
      *(float4*)&wnT[w * NPAD + nbase] = o;
    }
  }
}

// ---------------- Main GEMM: P = A (6144x768) * Qt^T (768x4096), fused w-reduction epilogue.
// LDS-traffic-minimal config: 192x256 block, FOUR waves of 96x128 (acc 192 regs).
// Read bytes/unit = 4x(96+128) rows = 896 (vs r12's 1280, -30%). Ring-2 LDS 57KB ->
// TWO co-resident blocks/CU (independent barrier domains hide each other's bursts).
// Grid 512 = exactly one round of 2/CU. 7 stage loads/wave/unit, vmcnt(7) 1-unit lead.
__global__ __launch_bounds__(THREADS, 2)
void gemm_main(const unsigned short* __restrict__ A,   // [6144][768] bf16 bits
               const unsigned short* __restrict__ Qt,  // [4096][768] bf16 bits
               const float* __restrict__ wnT,          // [48][4096]
               const float* __restrict__ bias,         // [4000]
               float* __restrict__ out) {              // [128][4000]
  __shared__ unsigned short S[2 * SLOT_ELEMS];   // 57344 B -> 2 blocks/CU

  int tid = threadIdx.x;
  int lane = tid & 63;
  int wid = tid >> 6;          // 0..3
  int wm = wid >> 1;           // 0..1 -> 96-row slice
  int wn = wid & 1;            // 0..1 -> 128-col half

  // 512 blocks: XCD k (= bid&7) owns by in [4k, 4k+4) (A-share 1.15MB, L2-resident),
  // sweeps 16 bx-groups.
  int bid = blockIdx.x;        // 0..511
  int xcd = bid & 7;
  int i = bid >> 3;            // 0..63
  int by = xcd * 4 + (i & 3);  // 0..31
  int bxg = i >> 2;            // 0..15
  int n0 = bxg * BNB;
  int m0 = by * BM;

  // ---- staging: per wave 3 A-chunks + 4 B-chunks per unit (chunk: 16 rows x 32 elems = 1KB).
  // LDS dest linear; global source granule XOR-pre-swizzled (granule 16B, row 64B):
  // LDS[row][g*8..] holds global[row][(g ^ ((row>>1)&3))*8..].
  int lrow = lane >> 2;              // 0..15 row within chunk
  int g = lane & 3;                  // granule
  int gsw = (g ^ ((lrow >> 1) & 3)) * 8;
  const unsigned short* gsrc[7];
  int ldst[7];
  #pragma unroll
  for (int j = 0; j < 3; ++j) {      // A chunks: wid*3+j (0..11)
    int c = wid * 3 + j;
    gsrc[j] = A + (size_t)(m0 + c * 16 + lrow) * KD + gsw;
    ldst[j] = c * 512;
  }
  #pragma unroll
  for (int j = 0; j < 4; ++j) {      // B chunks: wid*4+j (0..15)
    int c = wid * 4 + j;
    gsrc[3 + j] = Qt + (size_t)(n0 + c * 16 + lrow) * KD + gsw;
    ldst[3 + j] = AELEMS + c * 512;
  }

#define SLOTB(u) (((u) & 1) * SLOT_ELEMS)
#define STAGE(u)                                                                  \
  { _Pragma("unroll")                                                             \
    for (int j = 0; j < 7; ++j)                                                   \
      __builtin_amdgcn_global_load_lds(                                           \
          (const __attribute__((address_space(1))) void*)(gsrc[j] + (u) * BKU),   \
          (__attribute__((address_space(3))) void*)(&S[SLOTB(u) + ldst[j]]), 16, 0, 0); }

  // ---- ds_read offsets (elem); rows 32 elems (64B); swizzle matches staging
  // ((row>>1)&3 == ((row%16)>>1)&3 since 16 | chunk stride).
  int q16 = lane & 15;
  int hi = lane >> 4;                // 0..3 -> k-granule
  int kgr = (hi ^ ((q16 >> 1) & 3)) * 8;
  int arow = (wm * 96 + q16) * BKU + kgr;             // + mi*512
  int brow = AELEMS + (wn * 128 + q16) * BKU + kgr;   // + ni*512

  f32x4 acc[6][8] = {};              // [mi][ni] -- 192 regs
  short8 af[6];
  short8 bf[4];                      // single buffer, two ni-half passes

  // Prologue: stage unit 0.
  STAGE(0);

  #pragma unroll
  for (int u = 0; u < UNITS; ++u) {
    if (u + 1 < UNITS) {
      STAGE(u + 1);                  // 7 loads -> other slot (1-unit DMA lead)
      asm volatile("s_waitcnt vmcnt(7)" ::: "memory");   // unit u's 7 landed
    } else {
      asm volatile("s_waitcnt vmcnt(0)" ::: "memory");
    }
    __builtin_amdgcn_s_barrier();    // all waves: slot u ready; slot u-1 consumed
    __builtin_amdgcn_sched_barrier(0);

    const unsigned short* sb = &S[SLOTB(u)];
    #pragma unroll
    for (int mi = 0; mi < 6; ++mi)
      af[mi] = *(const short8*)&sb[arow + mi * 512];
    #pragma unroll
    for (int ni = 0; ni < 4; ++ni)
      bf[ni] = *(const short8*)&sb[brow + ni * 512];
    asm volatile("s_waitcnt lgkmcnt(0)" ::: "memory");
    __builtin_amdgcn_sched_barrier(0);
    __builtin_amdgcn_s_setprio(1);
    #pragma unroll
    for (int ni = 0; ni < 4; ++ni)
      #pragma unroll
      for (int mi = 0; mi < 6; ++mi)
        acc[mi][ni] = __builtin_amdgcn_mfma_f32_16x16x32_bf16(af[mi], bf[ni], acc[mi][ni], 0, 0, 0);
    __builtin_amdgcn_s_setprio(0);
    #pragma unroll
    for (int ni = 0; ni < 4; ++ni)
      bf[ni] = *(const short8*)&sb[brow + (4 + ni) * 512];
    asm volatile("s_waitcnt lgkmcnt(0)" ::: "memory");
    __builtin_amdgcn_sched_barrier(0);
    __builtin_amdgcn_s_setprio(1);
    #pragma unroll
    for (int ni = 0; ni < 4; ++ni)
      #pragma unroll
      for (int mi = 0; mi < 6; ++mi)
        acc[mi][4 + ni] = __builtin_amdgcn_mfma_f32_16x16x32_bf16(af[mi], bf[ni], acc[mi][4 + ni], 0, 0, 0);
    __builtin_amdgcn_s_setprio(0);
    __builtin_amdgcn_sched_barrier(0);
    // all ds_reads of slot u are consumed before this wave's next barrier -> ring-2 safe
  }

  // ---- Epilogue: y[b,n] = sum_w wnT[w][n] * P[(b,w),n] + bias[n]
  // wave rows: wm*96 + mi*16 + hi*4 + r; batch = by*4 + wm*2 + (mi>=3); w = (mi%3)*16+hi*4+r.
  int b0 = by * 4 + wm * 2;
  #pragma unroll
  for (int ni = 0; ni < 8; ++ni) {
    int ng = n0 + wn * 128 + ni * 16 + q16;
    float s0 = 0.f, s1 = 0.f;
    #pragma unroll
    for (int mi = 0; mi < 3; ++mi) {
      int wbase = mi * 16 + hi * 4;
      f32x4 va = acc[mi][ni];
      f32x4 vb = acc[mi + 3][ni];
      #pragma unroll
      for (int r = 0; r < 4; ++r) {
        float t = wnT[(wbase + r) * NPAD + ng];
        s0 += t * va[r];
        s1 += t * vb[r];
      }
    }
    s0 += __shfl_xor(s0, 16); s0 += __shfl_xor(s0, 32);
    s1 += __shfl_xor(s1, 16); s1 += __shfl_xor(s1, 32);
    if (hi == 0 && ng < OUTD) {
      float bv = bias[ng];
      out[(size_t)b0 * OUTD + ng] = s0 + bv;
      out[(size_t)(b0 + 1) * OUTD + ng] = s1 + bv;
    }
  }
#undef STAGE
#undef SLOTB
}

extern "C" void kernel_launch(void* const* d_in, const int* in_sizes, int n_in,
                              void* d_out, int out_size, void* d_ws, size_t ws_size,
                              hipStream_t stream) {
  const float* x      = (const float*)d_in[0];
  const float* width  = (const float*)d_in[1];
  const float* height = (const float*)d_in[2];
  const float* feat   = (const float*)d_in[3];
  const float* bias   = (const float*)d_in[4];
  float* out = (float*)d_out;

  char* ws = (char*)d_ws;
  unsigned short* A  = (unsigned short*)ws;                        // 6144*768*2 = 9,437,184
  unsigned short* Qt = (unsigned short*)(ws + 9437184);            // 4096*768*2 = 6,291,456
  float* wnT         = (float*)(ws + 9437184 + 6291456);           // 48*4096*4  =   786,432

  prep_all<<<dim3(XPB + NPAD / 4), dim3(256), 0, stream>>>(x, width, height, feat, A, Qt, wnT);
  gemm_main<<<dim3(512), dim3(THREADS), 0, stream>>>(A, Qt, wnT, bias, out);
}